// Round 1
// baseline (142.434 us; speedup 1.0000x reference)
//
#include <hip/hip_runtime.h>

// KL( N(pm, ps^2) || N(qm, qs^2) ) over [32,128,32,64], sum/(B*L).
// kl_elem = 0.5*(r^2 + d^2 - 1) - log(r),  r = ps/qs, d = (qm-pm)/qs.
//
// R7/R8 (prev session): nt loads, depth-8, all 32 loads pinned up front
//   -> partial ~35-36us (read ~3.8 TB/s), but ~150 VGPR -> 3 blocks/CU
//   -> 1024-block grid runs a 256-block straggler round (25% of work).
// R9 (this round): split depth-8 into 2 chunks of depth-4 (16 loads in
//   flight per phase, 64 data VGPRs) + __launch_bounds__(256,4) so all
//   1024 blocks are co-resident (4 blocks/CU, zero tail). 16 waves/CU
//   x 16KB outstanding still >> what's needed to cover HBM latency.

constexpr int TOTAL  = 32 * 128 * 32 * 64;   // 8388608 elements
constexpr int N4     = TOTAL / 4;            // 2097152 float4 per array
constexpr int BLOCK  = 256;
constexpr int GRID   = 1024;
constexpr int TILE4  = N4 / GRID;            // 2048 float4 per array per block
constexpr int PT     = TILE4 / BLOCK;        // 8 batches per thread
constexpr int CHUNK  = 4;                    // batches per chunk
constexpr int NCHUNK = PT / CHUNK;           // 2 chunks
constexpr float INV_BL = 1.0f / (32.0f * 128.0f);

static_assert(PT == 8 && NCHUNK == 2, "depth-8 per-thread as 2x depth-4, exact");

typedef float f4 __attribute__((ext_vector_type(4)));

__device__ __forceinline__ f4 ntload(const float4* p) {
    return __builtin_nontemporal_load((const f4*)p);
}

__device__ __forceinline__ float kl_elem(float a, float b, float c, float d) {
    float inv = __builtin_amdgcn_rcpf(d);     // v_rcp_f32, ~1ulp (tol is 2%)
    float r   = b * inv;
    float df  = (c - a) * inv;
    return 0.5f * (r * r + df * df - 1.0f) - __logf(r);
}

__device__ __forceinline__ float kl_4(f4 a, f4 b, f4 c, f4 d) {
    return (kl_elem(a.x, b.x, c.x, d.x) + kl_elem(a.y, b.y, c.y, d.y))
         + (kl_elem(a.z, b.z, c.z, d.z) + kl_elem(a.w, b.w, c.w, d.w));
}

// One chunk: issue 16 nt loads (4 arrays x depth-4), fence, consume.
// Trailing fence keeps the next chunk's loads from hoisting over this
// chunk's compute (would re-create the 128-reg data peak).
__device__ __forceinline__ float chunk_accum(
    const float4* __restrict__ pm, const float4* __restrict__ ps,
    const float4* __restrict__ qm, const float4* __restrict__ qs,
    int base)
{
    f4 A[CHUNK], Bv[CHUNK], C[CHUNK], Dv[CHUNK];
    #pragma unroll
    for (int j = 0; j < CHUNK; ++j) {
        const int i = base + j * BLOCK;
        A[j]  = ntload(pm + i);
        Bv[j] = ntload(ps + i);
        C[j]  = ntload(qm + i);
        Dv[j] = ntload(qs + i);
    }
    __builtin_amdgcn_sched_barrier(0);   // loads stay issued above
    float accA = kl_4(A[0], Bv[0], C[0], Dv[0]) + kl_4(A[2], Bv[2], C[2], Dv[2]);
    float accB = kl_4(A[1], Bv[1], C[1], Dv[1]) + kl_4(A[3], Bv[3], C[3], Dv[3]);
    __builtin_amdgcn_sched_barrier(0);   // next chunk's loads stay below
    return accA + accB;
}

__global__ __launch_bounds__(BLOCK, 4) void kl_partial_kernel(
    const float4* __restrict__ pm, const float4* __restrict__ ps,
    const float4* __restrict__ qm, const float4* __restrict__ qs,
    float* __restrict__ partial)
{
    const int tbase = blockIdx.x * TILE4 + threadIdx.x;

    float acc = 0.0f;
    #pragma unroll
    for (int c = 0; c < NCHUNK; ++c)
        acc += chunk_accum(pm, ps, qm, qs, tbase + c * (CHUNK * BLOCK));

    // wave-64 reduction
    #pragma unroll
    for (int off = 32; off > 0; off >>= 1)
        acc += __shfl_down(acc, off, 64);

    __shared__ float smem[BLOCK / 64];
    const int lane = threadIdx.x & 63;
    const int wid  = threadIdx.x >> 6;
    if (lane == 0) smem[wid] = acc;
    __syncthreads();

    if (threadIdx.x == 0) {
        float t = 0.0f;
        #pragma unroll
        for (int w = 0; w < BLOCK / 64; ++w) t += smem[w];
        partial[blockIdx.x] = t;
    }
}

__global__ __launch_bounds__(256) void kl_final_kernel(
    const float* __restrict__ partial, float* __restrict__ out)
{
    float acc = 0.0f;
    for (int i = threadIdx.x; i < GRID; i += 256)
        acc += partial[i];

    #pragma unroll
    for (int off = 32; off > 0; off >>= 1)
        acc += __shfl_down(acc, off, 64);

    __shared__ float smem[4];
    const int lane = threadIdx.x & 63;
    const int wid  = threadIdx.x >> 6;
    if (lane == 0) smem[wid] = acc;
    __syncthreads();

    if (threadIdx.x == 0) {
        float t = 0.0f;
        #pragma unroll
        for (int w = 0; w < 4; ++w) t += smem[w];
        out[0] = t * INV_BL;
    }
}

extern "C" void kernel_launch(void* const* d_in, const int* in_sizes, int n_in,
                              void* d_out, int out_size, void* d_ws, size_t ws_size,
                              hipStream_t stream) {
    const float4* pm = (const float4*)d_in[0];  // prior_mu
    const float4* ps = (const float4*)d_in[1];  // prior_sigma
    const float4* qm = (const float4*)d_in[2];  // post_mu
    const float4* qs = (const float4*)d_in[3];  // post_sigma
    float* partial = (float*)d_ws;              // GRID floats = 4 KiB scratch
    float* out     = (float*)d_out;

    kl_partial_kernel<<<GRID, BLOCK, 0, stream>>>(pm, ps, qm, qs, partial);
    kl_final_kernel<<<1, 256, 0, stream>>>(partial, out);
}